// Round 20
// baseline (5061.452 us; speedup 1.0000x reference)
//
#include <hip/hip_runtime.h>
#include <hip/hip_cooperative_groups.h>

namespace cg = cooperative_groups;

#define Bb 64
#define Tt 512
#define Dd 512
#define Hh 2048
#define Oo 7
#define NKT 80          // 2560 / 32
#define NWG 256
#define NTHR 512        // 8 waves
#define SP 68           // LDS partials row stride (floats): 64 data cols + pad
#define HSTEP 131072    // shorts per Hbuf step: 64 nb * 64 b * 32
#define XSTEP 32768     // shorts per xbf step: 16 kt * 64 b * 32
#define WSLC (NKT * 512)   // shorts per ntw weight slice (80 KB)

typedef short bf16x8 __attribute__((ext_vector_type(8)));
typedef float f32x4 __attribute__((ext_vector_type(4)));

__device__ __forceinline__ unsigned short f2bf(float f) {
  unsigned u = __float_as_uint(f);
  return (unsigned short)((u + 0x7FFFu + ((u >> 16) & 1u)) >> 16);
}
__device__ __forceinline__ float bf2f(unsigned short s) {
  return __uint_as_float(((unsigned)s) << 16);
}
__device__ __forceinline__ float sigm(float x) { return 1.0f / (1.0f + __expf(-x)); }
__device__ __forceinline__ float tanh_(float x) {
  x = fminf(15.0f, fmaxf(-15.0f, x));
  float e = __expf(2.0f * x);
  return (e - 1.0f) / (e + 1.0f);
}

__global__ void __launch_bounds__(NTHR, 2) lstm_fused(
    const float* __restrict__ x,
    const float* __restrict__ W_ih, const float* __restrict__ b_ih,
    const float* __restrict__ W_hh, const float* __restrict__ b_hh,
    const float* __restrict__ W_h0, const float* __restrict__ b_h0,
    const float* __restrict__ W_c0, const float* __restrict__ b_c0,
    const float* __restrict__ W_fc, const float* __restrict__ b_fc,
    float* __restrict__ out,
    short* __restrict__ Wbf,            // [8192*2560] bf16, fragment-linear
    unsigned short* __restrict__ Hbuf,  // [513][64 nb][64 b][32] bf16 (BLOCKED)
    float* __restrict__ cbuf,           // [64][2048]
    float* __restrict__ meanx,          // [64][512]
    float* __restrict__ bsum,           // [8192]
    unsigned short* __restrict__ xbf,   // [512 t][16 kt][64 b][32] bf16 (BLOCKED)
    unsigned* __restrict__ flags)       // [256] per-WG step flag (monotonic)
{
  const int wg = blockIdx.x, tid = threadIdx.x;
  const int gtid = wg * NTHR + tid;
  cg::grid_group grid = cg::this_grid();
  __shared__ float smem[256 * SP];  // 69632 B: partials(256x68) / phase0 / fc staging

  // batch-split: pair (wg, wg+16) shares weights AND shares an XCD under both
  // contiguous (same /32 block) and round-robin (%8) placement.
  // WG owns batch rows [bh*32,+32) x h-cols [cgp*16,+16).
  const int bh = (wg >> 4) & 1;
  const int cgp = ((wg >> 5) << 4) | (wg & 15);   // 0..127

  // ---------- phase 0a: mean_x over T ----------
  {
    int b = wg >> 2;
    int d = ((wg & 3) << 7) + (tid & 127);
    int th = tid >> 7;                   // 0..3, 128 timesteps each
    const float* xp = x + (size_t)b * Tt * Dd + d;
    float s = 0.f;
    for (int t = th * 128; t < th * 128 + 128; ++t) s += xp[(size_t)t * Dd];
    smem[tid] = s;
    __syncthreads();
    if (tid < 128) {
      float tot = smem[tid] + smem[tid + 128] + smem[tid + 256] + smem[tid + 384];
      meanx[b * Dd + ((wg & 3) << 7) + tid] = tot * (1.0f / Tt);
    }
    __syncthreads();
  }

  // ---------- phase 0b: weight swizzle + x->bf16 (blocked) + bias sums + flags ----------
  {
    const int NSLOT = (8192 * 2560) / 8;
    for (int slot = gtid; slot < NSLOT; slot += NWG * NTHR) {
      int lane = slot & 63;
      int fr = slot >> 6;                 // ntw*80 + kt
      int kt = fr % 80;
      int ntw = fr / 80;
      int nl = ((ntw & 1) << 4) + (lane & 15);
      int w = ntw >> 1;
      int row = ((nl >> 3) << 11) + (w << 3) + (nl & 7);   // gate*2048 + w*8 + j
      int kb = (kt << 5) + ((lane >> 4) << 3);
      const float* src = (kb < 512) ? (W_ih + (size_t)row * 512 + kb)
                                    : (W_hh + (size_t)row * 2048 + (kb - 512));
      float4 u0 = *reinterpret_cast<const float4*>(src);
      float4 u1 = *reinterpret_cast<const float4*>(src + 4);
      bf16x8 v;
      v[0] = (short)f2bf(u0.x); v[1] = (short)f2bf(u0.y);
      v[2] = (short)f2bf(u0.z); v[3] = (short)f2bf(u0.w);
      v[4] = (short)f2bf(u1.x); v[5] = (short)f2bf(u1.y);
      v[6] = (short)f2bf(u1.z); v[7] = (short)f2bf(u1.w);
      *reinterpret_cast<bf16x8*>(Wbf + (size_t)slot * 8) = v;
    }
    // x -> xbf blocked: slot s -> [t][kt][b][q*8..+8)
    const int NX = (Bb * Tt * Dd) / 8;   // 2,097,152
    for (int s = gtid; s < NX; s += NWG * NTHR) {
      int q  = s & 3;
      int b  = (s >> 2) & 63;
      int kt = (s >> 8) & 15;
      int t  = s >> 12;
      const float* p = x + (size_t)b * (Tt * Dd) + (size_t)t * Dd + (kt << 5) + (q << 3);
      float4 u0 = *reinterpret_cast<const float4*>(p);
      float4 u1 = *reinterpret_cast<const float4*>(p + 4);
      bf16x8 v;
      v[0] = (short)f2bf(u0.x); v[1] = (short)f2bf(u0.y);
      v[2] = (short)f2bf(u0.z); v[3] = (short)f2bf(u0.w);
      v[4] = (short)f2bf(u1.x); v[5] = (short)f2bf(u1.y);
      v[6] = (short)f2bf(u1.z); v[7] = (short)f2bf(u1.w);
      *reinterpret_cast<bf16x8*>((short*)xbf + (size_t)s * 8) = v;
    }
    if (gtid < NWG)
      __hip_atomic_store(&flags[gtid], 0u, __ATOMIC_RELAXED, __HIP_MEMORY_SCOPE_AGENT);
    if (gtid < 8192) bsum[gtid] = b_ih[gtid] + b_hh[gtid];
  }
  grid.sync();

  // ---------- phase 0c: h0 / c0 for this WG's (32 b x 16 cols) ----------
  {
    for (int q2 = tid; q2 < 1024; q2 += NTHR) {
      int which = q2 >> 9;                // 0 -> h0, 1 -> c0
      int r = q2 & 511;
      int lb2 = r >> 4, j = r & 15;
      int b = (bh << 5) + lb2;
      int n = (cgp << 4) + j;
      const float* Wr = (which ? W_c0 : W_h0) + (size_t)n * 512;
      const float* mx = meanx + b * 512;
      float a0 = which ? b_c0[n] : b_h0[n];
      for (int d = 0; d < 512; ++d) a0 += mx[d] * Wr[d];
      if (which) cbuf[b * Hh + n] = a0;
      else       Hbuf[((n >> 5) << 11) + (b << 5) + (n & 31)] = f2bf(a0);
    }
  }
  grid.sync();

  const int wave = tid >> 6, lane = tid & 63;   // wave 0..7
  const int ml = lane & 15;
  const int kg = lane >> 4;
  // weight slice: 4 consecutive ntw slices (contiguous 320 KB region)
  const short* wbase = Wbf + (size_t)(cgp << 2) * WSLC;

  // ---------- cell state in registers: thread -> (b2 = tid>>4, jj = tid&15) ----------
  const int b2 = tid >> 4, jj = tid & 15;
  const int cbn = (bh << 5) + b2;          // global batch row
  const int cn  = (cgp << 4) + jj;         // global h col
  const int cbase = ((jj >> 3) << 5) + (jj & 7);   // LDS col base
  float cv = cbuf[cbn * Hh + cn];
  const float bi = bsum[cn],        bfs = bsum[2048 + cn];
  const float bg = bsum[4096 + cn], bo = bsum[6144 + cn];

  f32x4 acc[2][4];
#pragma unroll
  for (int mt = 0; mt < 2; ++mt)
#pragma unroll
    for (int q = 0; q < 4; ++q) acc[mt][q] = (f32x4){0.f, 0.f, 0.f, 0.f};

  // x-part of step tx+1's gates (recurrence-independent; runs under the wait)
  auto xpart = [&](int tx) {
#pragma unroll
    for (int i = 0; i < 2; ++i) {
      int kt = (wave << 1) + i;                       // 0..15
      const unsigned short* xb = xbf + (size_t)tx * XSTEP + ((size_t)kt << 11)
                                     + (bh << 10) + (kg << 3);
      bf16x8 afr[2];
#pragma unroll
      for (int mt = 0; mt < 2; ++mt)
        afr[mt] = *reinterpret_cast<const bf16x8*>(xb + (((mt << 4) + ml) << 5));
      const short* wk = wbase + ((size_t)kt << 9) + (lane << 3);
#pragma unroll
      for (int q = 0; q < 4; ++q) {
        bf16x8 bq = *reinterpret_cast<const bf16x8*>(wk + (size_t)q * WSLC);
#pragma unroll
        for (int mt = 0; mt < 2; ++mt)
          acc[mt][q] = __builtin_amdgcn_mfma_f32_16x16x32_bf16(afr[mt], bq, acc[mt][q], 0, 0, 0);
      }
    }
  };

  // per-wave producer wait: wave reads n-blocks [wave*8,+8) of batch half bh,
  // produced by WGs wg' = wave*32 + bh*16 + k (k 0..15). Poll those 16 flags.
  auto waitwave = [&](unsigned tw) {
    const unsigned* fl = flags + ((wave << 5) | (bh << 4) | (lane & 15));
    while (__hip_atomic_load(fl, __ATOMIC_RELAXED, __HIP_MEMORY_SCOPE_AGENT) < tw)
      __builtin_amdgcn_s_sleep(2);
    asm volatile("" ::: "memory");
  };

  // global wait (epilogue only)
  auto waitall = [&](unsigned tw) {
    if (wave == 0) {
      const unsigned* fl = flags + (lane << 2);
      for (;;) {
        unsigned m0 = __hip_atomic_load(&fl[0], __ATOMIC_RELAXED, __HIP_MEMORY_SCOPE_AGENT);
        unsigned m1 = __hip_atomic_load(&fl[1], __ATOMIC_RELAXED, __HIP_MEMORY_SCOPE_AGENT);
        unsigned m2 = __hip_atomic_load(&fl[2], __ATOMIC_RELAXED, __HIP_MEMORY_SCOPE_AGENT);
        unsigned m3 = __hip_atomic_load(&fl[3], __ATOMIC_RELAXED, __HIP_MEMORY_SCOPE_AGENT);
        unsigned mn = min(min(m0, m1), min(m2, m3));
        if (__all(mn >= tw)) break;
        __builtin_amdgcn_s_sleep(2);
      }
    }
    asm volatile("" ::: "memory");
    __syncthreads();
  };

  // prologue: x-part for step 1 (x index 0)
  xpart(0);

  // ---------- main recurrence ----------
  for (int t = 1; t <= Tt; ++t) {
    if (t > 1) waitwave((unsigned)(t - 1));
    // h-part: 8 n-blocks per wave; A reads 1KB contiguous (own batch half only)
#pragma unroll
    for (int i = 0; i < 8; ++i) {
      int nb = (wave << 3) + i;                       // 0..63
      const unsigned short* hb = Hbuf + (size_t)(t - 1) * HSTEP + ((size_t)nb << 11)
                                      + (bh << 10) + (kg << 3);
      bf16x8 afr[2];
#pragma unroll
      for (int mt = 0; mt < 2; ++mt)
        afr[mt] = *reinterpret_cast<const bf16x8*>(hb + (((mt << 4) + ml) << 5));
      const short* wk = wbase + ((size_t)(16 + nb) << 9) + (lane << 3);
#pragma unroll
      for (int q = 0; q < 4; ++q) {
        bf16x8 bq = *reinterpret_cast<const bf16x8*>(wk + (size_t)q * WSLC);
#pragma unroll
        for (int mt = 0; mt < 2; ++mt)
          acc[mt][q] = __builtin_amdgcn_mfma_f32_16x16x32_bf16(afr[mt], bq, acc[mt][q], 0, 0, 0);
      }
    }
    // partials -> LDS: row = wave*32 + mt*16 + kg*4 + r (0..255), col = q*16+ml,
    // stride SP=68: kg-group bank offset 4*68%32=16 -> exactly 2-way write (free)
#pragma unroll
    for (int mt = 0; mt < 2; ++mt) {
      int r0 = (wave << 5) + (mt << 4) + (kg << 2);
#pragma unroll
      for (int r = 0; r < 4; ++r) {
        float* sr = &smem[(r0 + r) * SP];
#pragma unroll
        for (int q = 0; q < 4; ++q) sr[(q << 4) + ml] = acc[mt][q][r];
      }
    }
    __syncthreads();
    // cell: reduce 8 wave-partials, LSTM nonlinearity (register cell state)
    unsigned* hout32 = (unsigned*)(Hbuf + (size_t)t * HSTEP);
    {
      float gi = 0.f, gf_ = 0.f, gg = 0.f, go = 0.f;
#pragma unroll
      for (int w2 = 0; w2 < 8; ++w2) {
        const float* sp = &smem[((w2 << 5) + b2) * SP + cbase];
        gi += sp[0]; gf_ += sp[8]; gg += sp[16]; go += sp[24];
      }
      gi += bi; gf_ += bfs; gg += bg; go += bo;
      cv = sigm(gf_) * cv + sigm(gi) * tanh_(gg);
      float hv = sigm(go) * tanh_(cv);
      float hv_hi = __shfl_down(hv, 1);   // partner jj+1, same b2
      if (!(tid & 1)) {
        unsigned pk = ((unsigned)f2bf(hv_hi) << 16) | (unsigned)f2bf(hv);
        int soff = ((cn >> 5) << 11) + (cbn << 5) + (cn & 31);
        __hip_atomic_store(&hout32[soff >> 1], pk,
                           __ATOMIC_RELAXED, __HIP_MEMORY_SCOPE_AGENT);
      }
    }
    // drain h stores, then publish this WG's step flag
    asm volatile("s_waitcnt vmcnt(0)" ::: "memory");
    __syncthreads();
    if (tid == 0)
      __hip_atomic_store(&flags[wg], (unsigned)t,
                         __ATOMIC_RELAXED, __HIP_MEMORY_SCOPE_AGENT);
    // wait-shadow work: x-part for step t+1
#pragma unroll
    for (int mt = 0; mt < 2; ++mt)
#pragma unroll
      for (int q = 0; q < 4; ++q) acc[mt][q] = (f32x4){0.f, 0.f, 0.f, 0.f};
    if (t < Tt) xpart(t);
  }

  // ---------- wait for ALL WGs' step-512 h before reading it ----------
  waitall((unsigned)Tt);

  // ---------- fc epilogue (stage W_fc f32 in smem, 14336 <= 17408 floats) ----------
  for (int i = tid; i < Oo * Hh; i += NTHR) smem[i] = W_fc[i];
  __syncthreads();
  if (gtid < Bb * Tt) {
    int b = gtid & 63, tq = gtid >> 6;
    const unsigned short* hrw = Hbuf + (size_t)(tq + 1) * HSTEP + (b << 5);
    float acco[7];
#pragma unroll
    for (int o = 0; o < 7; ++o) acco[o] = b_fc[o];
    for (int k = 0; k < Hh; k += 8) {
      bf16x8 hv = *reinterpret_cast<const bf16x8*>(hrw + ((k >> 5) << 11) + (k & 31));
      float hf[8];
#pragma unroll
      for (int e = 0; e < 8; ++e) hf[e] = bf2f((unsigned short)hv[e]);
#pragma unroll
      for (int o = 0; o < 7; ++o) {
        const float* wr = &smem[o * Hh + k];
        float s = 0.f;
#pragma unroll
        for (int e = 0; e < 8; ++e) s += hf[e] * wr[e];
        acco[o] += s;
      }
    }
    float* op = out + ((size_t)b * Tt + tq) * Oo;
#pragma unroll
    for (int o = 0; o < 7; ++o) op[o] = acco[o];
  }
}

extern "C" void kernel_launch(void* const* d_in, const int* in_sizes, int n_in,
                              void* d_out, int out_size, void* d_ws, size_t ws_size,
                              hipStream_t stream) {
  (void)in_sizes; (void)n_in;
  const float* x    = (const float*)d_in[0];
  const float* W_ih = (const float*)d_in[1];
  const float* b_ih = (const float*)d_in[2];
  const float* W_hh = (const float*)d_in[3];
  const float* b_hh = (const float*)d_in[4];
  const float* W_h0 = (const float*)d_in[5];
  const float* b_h0 = (const float*)d_in[6];
  const float* W_c0 = (const float*)d_in[7];
  const float* b_c0 = (const float*)d_in[8];
  const float* W_fc = (const float*)d_in[9];
  const float* b_fc = (const float*)d_in[10];
  float* out = (float*)d_out;

  char* ws = (char*)d_ws;
  size_t off = 0;
  short* Wbf = (short*)(ws + off);            off += (size_t)8192 * 2560 * 2;
  unsigned short* Hbuf = (unsigned short*)(ws + off); off += (size_t)513 * 64 * 2048 * 2;
  float* cbuf = (float*)(ws + off);           off += (size_t)64 * 2048 * 4;
  float* meanx = (float*)(ws + off);          off += (size_t)64 * 512 * 4;
  float* bsum = (float*)(ws + off);           off += (size_t)8192 * 4;
  unsigned short* xbf = (unsigned short*)(ws + off); off += (size_t)64 * 512 * 512 * 2;
  unsigned* flags = (unsigned*)(ws + off);    off += (size_t)NWG * 4;

  if (ws_size < off) {
    hipMemsetAsync(d_out, 0, (size_t)out_size * 4, stream);
    return;
  }

  void* args[] = {&x, &W_ih, &b_ih, &W_hh, &b_hh, &W_h0, &b_h0, &W_c0, &b_c0,
                  &W_fc, &b_fc, &out, &Wbf, &Hbuf, &cbuf, &meanx, &bsum, &xbf, &flags};
  hipLaunchCooperativeKernel((void*)lstm_fused, dim3(NWG), dim3(NTHR), args, 0, stream);
}

// Round 21
// 3896.665 us; speedup vs baseline: 1.2989x; 1.2989x over previous
//
#include <hip/hip_runtime.h>
#include <hip/hip_cooperative_groups.h>

namespace cg = cooperative_groups;

#define Bb 64
#define Tt 512
#define Dd 512
#define Hh 2048
#define Oo 7
#define NKT 80          // 2560 / 32
#define NWG 256
#define NTHR 512        // 8 waves; grid=256 -> 1 block/CU
#define SP 36           // LDS partials row stride (floats): 2-way max bank aliasing
#define HSTEP 131072    // shorts per Hbuf step: 64 nb * 64 b * 32
#define XSTEP 32768     // shorts per xbf step: 16 kt * 64 b * 32

typedef short bf16x8 __attribute__((ext_vector_type(8)));
typedef float f32x4 __attribute__((ext_vector_type(4)));

#define LOADF(dst, p) \
  asm volatile("global_load_dwordx4 %0, %1, off" : "=v"(dst) : "v"(p))

__device__ __forceinline__ unsigned short f2bf(float f) {
  unsigned u = __float_as_uint(f);
  return (unsigned short)((u + 0x7FFFu + ((u >> 16) & 1u)) >> 16);
}
__device__ __forceinline__ float bf2f(unsigned short s) {
  return __uint_as_float(((unsigned)s) << 16);
}
__device__ __forceinline__ float sigm(float x) { return 1.0f / (1.0f + __expf(-x)); }
__device__ __forceinline__ float tanh_(float x) {
  x = fminf(15.0f, fmaxf(-15.0f, x));
  float e = __expf(2.0f * x);
  return (e - 1.0f) / (e + 1.0f);
}

__global__ void __launch_bounds__(NTHR, 1) lstm_fused(
    const float* __restrict__ x,
    const float* __restrict__ W_ih, const float* __restrict__ b_ih,
    const float* __restrict__ W_hh, const float* __restrict__ b_hh,
    const float* __restrict__ W_h0, const float* __restrict__ b_h0,
    const float* __restrict__ W_c0, const float* __restrict__ b_c0,
    const float* __restrict__ W_fc, const float* __restrict__ b_fc,
    float* __restrict__ out,
    short* __restrict__ Wbf,            // [8192*2560] bf16, fragment-linear
    unsigned short* __restrict__ Hbuf,  // [513][64 nb][64 b][32] bf16 (BLOCKED)
    float* __restrict__ cbuf,           // [64][2048]
    float* __restrict__ meanx,          // [64][512]
    float* __restrict__ bsum,           // [8192]
    unsigned short* __restrict__ xbf,   // [512 t][16 kt][64 b][32] bf16 (BLOCKED)
    unsigned* __restrict__ flags)       // [256] per-WG step flag (monotonic)
{
  const int wg = blockIdx.x, tid = threadIdx.x;
  const int gtid = wg * NTHR + tid;
  cg::grid_group grid = cg::this_grid();
  __shared__ float smem[8 * 64 * SP];  // 73728 B: partials / phase0 / fc staging

  // ---------- phase 0a: mean_x over T ----------
  {
    int b = wg >> 2;
    int d = ((wg & 3) << 7) + (tid & 127);
    int th = tid >> 7;                   // 0..3, 128 timesteps each
    const float* xp = x + (size_t)b * Tt * Dd + d;
    float s = 0.f;
    for (int t = th * 128; t < th * 128 + 128; ++t) s += xp[(size_t)t * Dd];
    smem[tid] = s;
    __syncthreads();
    if (tid < 128) {
      float tot = smem[tid] + smem[tid + 128] + smem[tid + 256] + smem[tid + 384];
      meanx[b * Dd + ((wg & 3) << 7) + tid] = tot * (1.0f / Tt);
    }
    __syncthreads();
  }

  // ---------- phase 0b: weight swizzle + x->bf16 (blocked) + bias sums + flags ----------
  {
    const int NSLOT = (8192 * 2560) / 8;
    for (int slot = gtid; slot < NSLOT; slot += NWG * NTHR) {
      int lane = slot & 63;
      int fr = slot >> 6;                 // ntw*80 + kt
      int kt = fr % 80;
      int ntw = fr / 80;
      int nl = ((ntw & 1) << 4) + (lane & 15);
      int w = ntw >> 1;
      int row = ((nl >> 3) << 11) + (w << 3) + (nl & 7);   // gate*2048 + w*8 + j
      int kb = (kt << 5) + ((lane >> 4) << 3);
      const float* src = (kb < 512) ? (W_ih + (size_t)row * 512 + kb)
                                    : (W_hh + (size_t)row * 2048 + (kb - 512));
      float4 u0 = *reinterpret_cast<const float4*>(src);
      float4 u1 = *reinterpret_cast<const float4*>(src + 4);
      bf16x8 v;
      v[0] = (short)f2bf(u0.x); v[1] = (short)f2bf(u0.y);
      v[2] = (short)f2bf(u0.z); v[3] = (short)f2bf(u0.w);
      v[4] = (short)f2bf(u1.x); v[5] = (short)f2bf(u1.y);
      v[6] = (short)f2bf(u1.z); v[7] = (short)f2bf(u1.w);
      *reinterpret_cast<bf16x8*>(Wbf + (size_t)slot * 8) = v;
    }
    // x -> xbf blocked: slot s -> [t][kt][b][q*8..+8)
    const int NX = (Bb * Tt * Dd) / 8;   // 2,097,152
    for (int s = gtid; s < NX; s += NWG * NTHR) {
      int q  = s & 3;
      int b  = (s >> 2) & 63;
      int kt = (s >> 8) & 15;
      int t  = s >> 12;
      const float* p = x + (size_t)b * (Tt * Dd) + (size_t)t * Dd + (kt << 5) + (q << 3);
      float4 u0 = *reinterpret_cast<const float4*>(p);
      float4 u1 = *reinterpret_cast<const float4*>(p + 4);
      bf16x8 v;
      v[0] = (short)f2bf(u0.x); v[1] = (short)f2bf(u0.y);
      v[2] = (short)f2bf(u0.z); v[3] = (short)f2bf(u0.w);
      v[4] = (short)f2bf(u1.x); v[5] = (short)f2bf(u1.y);
      v[6] = (short)f2bf(u1.z); v[7] = (short)f2bf(u1.w);
      *reinterpret_cast<bf16x8*>((short*)xbf + (size_t)s * 8) = v;
    }
    if (gtid < NWG)
      __hip_atomic_store(&flags[gtid], 0u, __ATOMIC_RELAXED, __HIP_MEMORY_SCOPE_AGENT);
    if (gtid < 8192) bsum[gtid] = b_ih[gtid] + b_hh[gtid];
  }
  grid.sync();

  // ---------- phase 0c: h0 / c0 (h0 in blocked layout) ----------
  {
    for (int q = tid; q < 1024; q += NTHR) {
      int which = q >> 9;                 // 0 -> h0, 1 -> c0
      int b = (q >> 3) & 63;
      int j = q & 7;
      int n = (wg << 3) + j;
      const float* Wr = (which ? W_c0 : W_h0) + (size_t)n * 512;
      const float* mx = meanx + b * 512;
      float acc0 = which ? b_c0[n] : b_h0[n];
      for (int d = 0; d < 512; ++d) acc0 += mx[d] * Wr[d];
      if (which) cbuf[b * Hh + n] = acc0;
      else       Hbuf[((n >> 5) << 11) + (b << 5) + (n & 31)] = f2bf(acc0);
    }
  }
  grid.sync();

  const int wave = tid >> 6, lane = tid & 63;   // wave 0..7
  const int ml = lane & 15;
  const int kg = lane >> 4;
  const short* wb0 = Wbf + (size_t)(wg * 2) * NKT * 512;  // frag stride = 512 shorts
  const short* wb1 = wb0 + (size_t)NKT * 512;

  // ---------- weight slice via asm loads (compiler keeps what it can) ----------
  bf16x8 w0x[2], w0h[8], w1x[2], w1h[8];
#pragma unroll
  for (int i = 0; i < 2; ++i) {
    int kt = (wave << 1) + i;            // 0..15
    LOADF(w0x[i], wb0 + ((size_t)kt << 9) + (lane << 3));
    LOADF(w1x[i], wb1 + ((size_t)kt << 9) + (lane << 3));
  }
#pragma unroll
  for (int i = 0; i < 8; ++i) {
    int kt = 16 + (wave << 3) + i;       // 16..79
    LOADF(w0h[i], wb0 + ((size_t)kt << 9) + (lane << 3));
    LOADF(w1h[i], wb1 + ((size_t)kt << 9) + (lane << 3));
  }
  asm volatile("s_waitcnt vmcnt(0)" ::: "memory");
  __builtin_amdgcn_sched_barrier(0);   // rule #18: MFMA must not hoist above the waitcnt

  // ---------- hoist loop-invariant cell state into registers (1 col/thread) ----------
  const int cb = tid >> 3, cj = tid & 7;
  const int cn = (wg << 3) + cj;
  float cv = cbuf[cb * Hh + cn];
  const float bi = bsum[cn],        bfs = bsum[2048 + cn];
  const float bg = bsum[4096 + cn], bo = bsum[6144 + cn];

  f32x4 acc[4][2];
#pragma unroll
  for (int mt = 0; mt < 4; ++mt) {
    acc[mt][0] = (f32x4){0.f, 0.f, 0.f, 0.f};
    acc[mt][1] = (f32x4){0.f, 0.f, 0.f, 0.f};
  }

  // x-part: blocked layout -> per (kt,mt) instr reads 1KB contiguous
  auto xpart = [&](int tx) {
#pragma unroll
    for (int i = 0; i < 2; ++i) {
      int kt = (wave << 1) + i;
      const unsigned short* xb = xbf + (size_t)tx * XSTEP + ((size_t)kt << 11) + (kg << 3);
      bf16x8 afr[4];
#pragma unroll
      for (int mt = 0; mt < 4; ++mt) {
        int m = (mt << 4) + ml;
        afr[mt] = *reinterpret_cast<const bf16x8*>(xb + (m << 5));
      }
#pragma unroll
      for (int mt = 0; mt < 4; ++mt) {
        acc[mt][0] = __builtin_amdgcn_mfma_f32_16x16x32_bf16(afr[mt], w0x[i], acc[mt][0], 0, 0, 0);
        acc[mt][1] = __builtin_amdgcn_mfma_f32_16x16x32_bf16(afr[mt], w1x[i], acc[mt][1], 0, 0, 0);
      }
    }
  };

  // per-wave producer wait
  auto waitwave = [&](unsigned tw) {
    const unsigned* fl = flags + ((wave << 5) | (lane & 31));
    while (__hip_atomic_load(fl, __ATOMIC_RELAXED, __HIP_MEMORY_SCOPE_AGENT) < tw)
      __builtin_amdgcn_s_sleep(2);
    asm volatile("" ::: "memory");
  };

  auto waitall = [&](unsigned tw) {
    if (wave == 0) {
      const unsigned* fl = flags + (lane << 2);
      for (;;) {
        unsigned m0 = __hip_atomic_load(&fl[0], __ATOMIC_RELAXED, __HIP_MEMORY_SCOPE_AGENT);
        unsigned m1 = __hip_atomic_load(&fl[1], __ATOMIC_RELAXED, __HIP_MEMORY_SCOPE_AGENT);
        unsigned m2 = __hip_atomic_load(&fl[2], __ATOMIC_RELAXED, __HIP_MEMORY_SCOPE_AGENT);
        unsigned m3 = __hip_atomic_load(&fl[3], __ATOMIC_RELAXED, __HIP_MEMORY_SCOPE_AGENT);
        unsigned mn = min(min(m0, m1), min(m2, m3));
        if (__all(mn >= tw)) break;
        __builtin_amdgcn_s_sleep(2);
      }
    }
    asm volatile("" ::: "memory");
    __syncthreads();
  };

  // prologue: x-part for step 1 (x index 0)
  xpart(0);

  // ---------- main recurrence ----------
  for (int t = 1; t <= Tt; ++t) {
    if (t > 1) waitwave((unsigned)(t - 1));
    // h-part: blocked layout -> only h loads post-wait
#pragma unroll
    for (int i = 0; i < 8; ++i) {
      int kth = (wave << 3) + i;         // h k-tile = n-block 0..63
      const unsigned short* hb = Hbuf + (size_t)(t - 1) * HSTEP + ((size_t)kth << 11) + (kg << 3);
      bf16x8 afr[4];
#pragma unroll
      for (int mt = 0; mt < 4; ++mt) {
        int m = (mt << 4) + ml;
        afr[mt] = *reinterpret_cast<const bf16x8*>(hb + (m << 5));
      }
#pragma unroll
      for (int mt = 0; mt < 4; ++mt) {
        acc[mt][0] = __builtin_amdgcn_mfma_f32_16x16x32_bf16(afr[mt], w0h[i], acc[mt][0], 0, 0, 0);
        acc[mt][1] = __builtin_amdgcn_mfma_f32_16x16x32_bf16(afr[mt], w1h[i], acc[mt][1], 0, 0, 0);
      }
    }
    // partials -> LDS (SP=36, <=2-way bank aliasing)
#pragma unroll
    for (int mt = 0; mt < 4; ++mt) {
      int r0 = (mt << 4) + (kg << 2);
#pragma unroll
      for (int r = 0; r < 4; ++r) {
        smem[((wave << 6) + r0 + r) * SP + ml] = acc[mt][0][r];
        smem[((wave << 6) + r0 + r) * SP + 16 + ml] = acc[mt][1][r];
      }
    }
    __syncthreads();
    // cell: reduce 8 wave-partials, LSTM nonlinearity (register cell state)
    unsigned* hout32 = (unsigned*)(Hbuf + (size_t)t * HSTEP);
    {
      float gi = 0.f, gf_ = 0.f, gg = 0.f, go = 0.f;
#pragma unroll
      for (int w2 = 0; w2 < 8; ++w2) {
        const float* sp = &smem[((w2 << 6) + cb) * SP];
        gi += sp[cj];       gf_ += sp[8 + cj];
        gg += sp[16 + cj];  go += sp[24 + cj];
      }
      gi += bi; gf_ += bfs; gg += bg; go += bo;
      cv = sigm(gf_) * cv + sigm(gi) * tanh_(gg);
      float hv = sigm(go) * tanh_(cv);
      float hv_hi = __shfl_down(hv, 1);
      if (!(tid & 1)) {
        unsigned pk = ((unsigned)f2bf(hv_hi) << 16) | (unsigned)f2bf(hv);
        int soff = ((cn >> 5) << 11) + (cb << 5) + (cn & 31);
        __hip_atomic_store(&hout32[soff >> 1], pk,
                           __ATOMIC_RELAXED, __HIP_MEMORY_SCOPE_AGENT);
      }
    }
    // drain h stores, then publish this WG's step flag
    asm volatile("s_waitcnt vmcnt(0)" ::: "memory");
    __syncthreads();
    if (tid == 0)
      __hip_atomic_store(&flags[wg], (unsigned)t,
                         __ATOMIC_RELAXED, __HIP_MEMORY_SCOPE_AGENT);
    // wait-shadow work: x-part for step t+1
#pragma unroll
    for (int mt = 0; mt < 4; ++mt) {
      acc[mt][0] = (f32x4){0.f, 0.f, 0.f, 0.f};
      acc[mt][1] = (f32x4){0.f, 0.f, 0.f, 0.f};
    }
    if (t < Tt) xpart(t);
  }

  // ---------- wait for ALL WGs' step-512 h before reading it ----------
  waitall((unsigned)Tt);

  // ---------- fc epilogue (stage W_fc f32 in smem) ----------
  for (int i = tid; i < Oo * Hh; i += NTHR) smem[i] = W_fc[i];
  __syncthreads();
  if (gtid < Bb * Tt) {
    int b = gtid & 63, tq = gtid >> 6;
    const unsigned short* hrw = Hbuf + (size_t)(tq + 1) * HSTEP + (b << 5);
    float acco[7];
#pragma unroll
    for (int o = 0; o < 7; ++o) acco[o] = b_fc[o];
    for (int k = 0; k < Hh; k += 8) {
      bf16x8 hv = *reinterpret_cast<const bf16x8*>(hrw + ((k >> 5) << 11) + (k & 31));
      float hf[8];
#pragma unroll
      for (int e = 0; e < 8; ++e) hf[e] = bf2f((unsigned short)hv[e]);
#pragma unroll
      for (int o = 0; o < 7; ++o) {
        const float* wr = &smem[o * Hh + k];
        float s = 0.f;
#pragma unroll
        for (int e = 0; e < 8; ++e) s += hf[e] * wr[e];
        acco[o] += s;
      }
    }
    float* op = out + ((size_t)b * Tt + tq) * Oo;
#pragma unroll
    for (int o = 0; o < 7; ++o) op[o] = acco[o];
  }
}

extern "C" void kernel_launch(void* const* d_in, const int* in_sizes, int n_in,
                              void* d_out, int out_size, void* d_ws, size_t ws_size,
                              hipStream_t stream) {
  (void)in_sizes; (void)n_in;
  const float* x    = (const float*)d_in[0];
  const float* W_ih = (const float*)d_in[1];
  const float* b_ih = (const float*)d_in[2];
  const float* W_hh = (const float*)d_in[3];
  const float* b_hh = (const float*)d_in[4];
  const float* W_h0 = (const float*)d_in[5];
  const float* b_h0 = (const float*)d_in[6];
  const float* W_c0 = (const float*)d_in[7];
  const float* b_c0 = (const float*)d_in[8];
  const float* W_fc = (const float*)d_in[9];
  const float* b_fc = (const float*)d_in[10];
  float* out = (float*)d_out;

  char* ws = (char*)d_ws;
  size_t off = 0;
  short* Wbf = (short*)(ws + off);            off += (size_t)8192 * 2560 * 2;
  unsigned short* Hbuf = (unsigned short*)(ws + off); off += (size_t)513 * 64 * 2048 * 2;
  float* cbuf = (float*)(ws + off);           off += (size_t)64 * 2048 * 4;
  float* meanx = (float*)(ws + off);          off += (size_t)64 * 512 * 4;
  float* bsum = (float*)(ws + off);           off += (size_t)8192 * 4;
  unsigned short* xbf = (unsigned short*)(ws + off); off += (size_t)64 * 512 * 512 * 2;
  unsigned* flags = (unsigned*)(ws + off);    off += (size_t)NWG * 4;

  if (ws_size < off) {
    hipMemsetAsync(d_out, 0, (size_t)out_size * 4, stream);
    return;
  }

  void* args[] = {&x, &W_ih, &b_ih, &W_hh, &b_hh, &W_h0, &b_h0, &W_c0, &b_c0,
                  &W_fc, &b_fc, &out, &Wbf, &Hbuf, &cbuf, &meanx, &bsum, &xbf, &flags};
  hipLaunchCooperativeKernel((void*)lstm_fused, dim3(NWG), dim3(NTHR), args, 0, stream);
}